// Round 15
// baseline (458.624 us; speedup 1.0000x reference)
//
#include <hip/hip_runtime.h>
#include <hip/hip_bf16.h>
#include <math.h>
#include <stdint.h>

#define BT  4096
#define DIM 1024
#define HID 4096
#define NE  8
#define TMX 72   // max active 128-row m-blocks

typedef __attribute__((ext_vector_type(8))) short short8v;
typedef __attribute__((ext_vector_type(4))) float f32x4;
typedef unsigned short ushort_t;

typedef __attribute__((address_space(1))) const void gas_void;
typedef __attribute__((address_space(3))) void las_void;
#define GLOAD_LDS16(g, l) __builtin_amdgcn_global_load_lds((gas_void*)(g), (las_void*)(l), 16, 0, 0)

__device__ inline ushort_t f2bf(float f) {
  __hip_bfloat16 b = __float2bfloat16(f);
  union { __hip_bfloat16 h; ushort_t u; } cv;
  cv.h = b;
  return cv.u;
}

// ============================================================================
// Transpose body (R15): 512 src-rows x 16 src-cols per block, 256 threads.
// Phase 1: 8x coalesced float4 reads/thread (4 thr/row = 64B segments),
//   convert fp32->bf16 IN REGISTERS, scatter-write ushort to lt[16][520].
//   Writes have no dependent consumer -> no latency chain (the old design's
//   16-deep scalar ds_read chain per packed store was the stall).
// Phase 2: per dst row c: one wave ds_read_b128 sweep (quad-starts
//   (4c+4*lane)%32 -> conflict-free) + 1KB fully-contiguous global write
//   (vs 128B segments before).
// ============================================================================
__device__ __forceinline__ void transpose512(
    const float* __restrict__ src, ushort_t* __restrict__ dst,
    int R, int C, int r0, int c0, int e, ushort_t (*lt)[520]) {
  const float* s = src + (size_t)e * R * C;
  ushort_t* d = dst + (size_t)e * R * C;
  int t = threadIdx.x;
#pragma unroll
  for (int i = 0; i < 8; i++) {
    int q = i * 256 + t;
    int r = q >> 2, c4 = (q & 3) * 4;
    float4 v = *(const float4*)&s[(size_t)(r0 + r) * C + c0 + c4];
    lt[c4 + 0][r] = f2bf(v.x);
    lt[c4 + 1][r] = f2bf(v.y);
    lt[c4 + 2][r] = f2bf(v.z);
    lt[c4 + 3][r] = f2bf(v.w);
  }
  __syncthreads();
  int wid = t >> 6, lane = t & 63;
#pragma unroll
  for (int ii = 0; ii < 4; ii++) {
    int c = wid + 4 * ii;
    short8v ov = *(const short8v*)&lt[c][lane * 8];
    *(short8v*)&d[(size_t)(c0 + c) * R + r0 + lane * 8] = ov;
  }
}

// ============================================================================
// Merged pre-pass: w1t (4096 blocks) ∥ w2t (4096) ∥ prep+router (4096).
// cur[] zeroed by a 32B memset before this kernel.
// ============================================================================
__global__ __launch_bounds__(256) void k_prepass(
    const float* __restrict__ x, const float* __restrict__ wg,
    ushort_t* __restrict__ xbf, float* __restrict__ logits_out,
    float* __restrict__ probs01, int* __restrict__ assign,
    int* __restrict__ cur,
    const float* __restrict__ w1, ushort_t* __restrict__ wt1,
    const float* __restrict__ w2, ushort_t* __restrict__ wt2) {
  __shared__ __attribute__((aligned(16))) ushort_t lt[16][520];
  int id = blockIdx.x;
  if (id < 4096) {                             // w1t: e*512 + rt*256 + ct
    int e = id >> 9, rt = (id >> 8) & 1, ct = id & 255;
    transpose512(w1, wt1, DIM, HID, rt * 512, ct * 16, e, lt);
    return;
  }
  if (id < 8192) {                             // w2t: e*512 + rt*64 + ct
    int q = id - 4096;
    int e = q >> 9, rt = (q >> 6) & 7, ct = q & 63;
    transpose512(w2, wt2, HID, DIM, rt * 512, ct * 16, e, lt);
    return;
  }
  int t = id - 8192;                           // token 0..4095
  int tid = threadIdx.x;
  const float* xr = x + (size_t)t * DIM;
  float4 v = ((const float4*)xr)[tid];
  ushort4 o;
  o.x = f2bf(v.x); o.y = f2bf(v.y); o.z = f2bf(v.z); o.w = f2bf(v.w);
  ((ushort4*)(xbf + (size_t)t * DIM))[tid] = o;

  float vv[4] = {v.x, v.y, v.z, v.w};
  float part[NE];
#pragma unroll
  for (int e = 0; e < NE; e++) part[e] = 0.f;
#pragma unroll
  for (int i = 0; i < 4; i++) {
    const float4* wr = (const float4*)(wg + (size_t)(tid * 4 + i) * NE);
    float4 a = wr[0], b = wr[1];
    part[0] += vv[i] * a.x; part[1] += vv[i] * a.y;
    part[2] += vv[i] * a.z; part[3] += vv[i] * a.w;
    part[4] += vv[i] * b.x; part[5] += vv[i] * b.y;
    part[6] += vv[i] * b.z; part[7] += vv[i] * b.w;
  }
#pragma unroll
  for (int e = 0; e < NE; e++)
    for (int off = 32; off > 0; off >>= 1)
      part[e] += __shfl_xor(part[e], off);

  float (*red)[NE] = (float(*)[NE])lt;
  int lane = tid & 63, wv = tid >> 6;
  if (lane == 0) {
#pragma unroll
    for (int e = 0; e < NE; e++) red[wv][e] = part[e];
  }
  __syncthreads();
  if (tid == 0) {
    float s8[NE];
#pragma unroll
    for (int e = 0; e < NE; e++)
      s8[e] = red[0][e] + red[1][e] + red[2][e] + red[3][e];
    float m = s8[0];
    for (int e = 1; e < NE; e++) m = fmaxf(m, s8[e]);
    float p[NE], s = 0.f;
    for (int e = 0; e < NE; e++) { p[e] = expf(s8[e] - m); s += p[e]; }
    float inv = 1.f / s;
    for (int e = 0; e < NE; e++) p[e] *= inv;
    for (int e = 0; e < NE; e++) logits_out[(size_t)t * NE + e] = s8[e];
    probs01[t * 2 + 0] = p[0];
    probs01[t * 2 + 1] = p[1];
    int b0 = 0;
    for (int e = 1; e < NE; e++) if (p[e] > p[b0]) b0 = e;
    int b1 = (b0 == 0) ? 1 : 0;
    for (int e = 0; e < NE; e++) if (e != b0 && p[e] > p[b1]) b1 = e;
    int pos0 = atomicAdd(&cur[b0], 1);
    assign[b0 * BT + pos0] = t * 2 + 0;
    int pos1 = atomicAdd(&cur[b1], 1);
    assign[b1 * BT + pos1] = t * 2 + 1;
  }
}

// -------- plan: prefix offsets + flattened active 128-row block list --------
__global__ void k_plan(const int* __restrict__ cur, int* __restrict__ segoff,
                       int* __restrict__ blk_e, int* __restrict__ blk_m0) {
  if (threadIdx.x == 0 && blockIdx.x == 0) {
    int s = 0;
    for (int e = 0; e < NE; e++) { segoff[e] = s; s += cur[e]; }
    int t = 0;
    for (int e = 0; e < NE; e++) {
      int mb = (cur[e] + 127) >> 7;
      for (int i = 0; i < mb; i++) { blk_e[t] = e; blk_m0[t] = i << 7; t++; }
    }
    for (; t < TMX; t++) { blk_e[t] = -1; blk_m0[t] = 0; }
  }
}

// ============================================================================
// GEMM core (R12, verified 139us/55% occ): 128x128 tile, BK=32, RING-3 LDS
// = 48 KiB -> 3 blocks/CU, 512 thr = 8 waves (2M x 4N), wave tile 64x32,
// acc[4][2].  24 waves/CU = 6 waves/SIMD — the occupancy optimum:
// 2/4/6/8 waves/SIMD = 181/155/139/265(spill!) us.  launch_bounds(512,6)
// keeps VGPR=40 (no spill; (512,8) forced VGPR=32 -> 374MB scratch, R13).
// Per K-tile: reads(t, slot t%3) -> STAGE(t+2 -> slot (t+2)%3) -> vmcnt(2)
//   -> barrier -> sched_barrier -> setprio -> 8 MFMA -> setprio.
// ============================================================================
#define VM2 asm volatile("s_waitcnt vmcnt(2)" ::: "memory")
#define VM0 asm volatile("s_waitcnt vmcnt(0)" ::: "memory")
#define VMN do {} while (0)

#define TILEK(TB, T, VMX, DOSTG)                                                \
  { short8v bv[2], af[4];                                                       \
    _Pragma("unroll")                                                           \
    for (int n = 0; n < 2; n++)                                                 \
      bv[n] = *(const short8v*)&Bv[TB][wn * 32 + n * 16 + lr][xsw];             \
    _Pragma("unroll")                                                           \
    for (int m = 0; m < 4; m++)                                                 \
      af[m] = *(const short8v*)&A[TB][wm * 64 + m * 16 + lr][xsw];              \
    if (DOSTG) { STAGE((((TB) + 2) % 3), ((T) + 2) * 32); }                     \
    VMX;                                                                        \
    __builtin_amdgcn_s_barrier();                                               \
    __builtin_amdgcn_sched_barrier(0);                                          \
    __builtin_amdgcn_s_setprio(1);                                              \
    _Pragma("unroll")                                                           \
    for (int m = 0; m < 4; m++)                                                 \
      _Pragma("unroll")                                                         \
      for (int n = 0; n < 2; n++)                                               \
        acc[m][n] = __builtin_amdgcn_mfma_f32_16x16x32_bf16(af[m], bv[n],       \
                                                            acc[m][n], 0, 0, 0);\
    __builtin_amdgcn_s_setprio(0); }

// ============================================================================
// GEMM1: h = gelu(x_gathered @ w1^T + b1).  Grid 32n x TMX(72)m = 2304.
// ============================================================================
__global__ __launch_bounds__(512, 6) void k_gemm1(
    const ushort_t* __restrict__ xbf, const ushort_t* __restrict__ wt1,
    const float* __restrict__ b1,
    const int* __restrict__ assign, const int* __restrict__ cur,
    const int* __restrict__ segoff, const int* __restrict__ blk_e,
    const int* __restrict__ blk_m0, ushort_t* __restrict__ hbuf) {
  const int nwg = 32 * TMX;                    // 2304, divisible by 8
  int f = blockIdx.x;
  int lg = (f & 7) * (nwg >> 3) + (f >> 3);    // XCD chunk swizzle (bijective)
  int m_idx = lg % TMX;                        // m-inner: chunk reuses B-panels
  int n_idx = lg / TMX;
  int e = blk_e[m_idx];
  if (e < 0) return;
  int m0 = blk_m0[m_idx];
  int count = cur[e];
  int n0 = n_idx << 7;

  __shared__ __attribute__((aligned(16))) ushort_t A[3][128][32];
  __shared__ __attribute__((aligned(16))) ushort_t Bv[3][128][32];
  int tid = threadIdx.x;
  int lane = tid & 63, wid = tid >> 6;

  int srow = lane >> 2;                        // 0..15 within wave's 16 rows
  int sunit = ((lane & 3) ^ ((lane >> 3) & 3)) << 3;
  int pA0 = m0 + wid * 16 + srow;
  int tok0 = (pA0 < count) ? (assign[e * BT + pA0] >> 1) : 0;
  const ushort_t* gA0 = xbf + (size_t)tok0 * DIM + sunit;
  const ushort_t* gB0 = wt1 + ((size_t)e * HID + n0 + wid * 16 + srow) * DIM + sunit;

  int wm = wid >> 2, wn = wid & 3;             // wave tile: 64(m) x 32(n)
  int lr = lane & 15, g = lane >> 4;
  int xsw = ((g ^ ((lr >> 1) & 3)) << 3);
  f32x4 acc[4][2];
  f32x4 zero = {0.f, 0.f, 0.f, 0.f};
#pragma unroll
  for (int m = 0; m < 4; m++)
#pragma unroll
    for (int n = 0; n < 2; n++) acc[m][n] = zero;

#define STAGE(SL, K0)                                          \
  { GLOAD_LDS16(gA0 + (K0), &A[SL][wid * 16][0]);              \
    GLOAD_LDS16(gB0 + (K0), &Bv[SL][wid * 16][0]); }

  STAGE(0, 0);
  STAGE(1, 32);
  VM2;
  __builtin_amdgcn_s_barrier();
  __builtin_amdgcn_sched_barrier(0);

  const int NT = DIM / 32;                     // 32
  for (int t = 0; t < NT - 2; t += 3) {        // t = 0,3,...,27
    TILEK(0, t + 0, VM2, 1);
    TILEK(1, t + 1, VM2, 1);
    TILEK(2, t + 2, VM2, 1);
  }
  TILEK(0, NT - 2, VM0, 0);                    // tile 30, slot 0
  TILEK(1, NT - 1, VMN, 0);                    // tile 31, slot 1
#undef STAGE

  int so = segoff[e];
#pragma unroll
  for (int m = 0; m < 4; m++) {
#pragma unroll
    for (int j = 0; j < 4; j++) {
      int p = m0 + wm * 64 + m * 16 + g * 4 + j;
      if (p >= count) continue;
      ushort_t* hr = hbuf + (size_t)(so + p) * HID;
#pragma unroll
      for (int n = 0; n < 2; n++) {
        int col = n0 + wn * 32 + n * 16 + lr;
        float v = acc[m][n][j] + b1[e * HID + col];
        float gl = 0.5f * v * (1.0f + erff(v * 0.70710678118654752f));
        hr[col] = f2bf(gl);
      }
    }
  }
}

// ============================================================================
// GEMM2: contrib[slot][t] = h @ w2^T + b2.  Grid 8n x TMX(72)m = 576.
// 576 <= 768 -> the whole grid is co-resident (single dispatch round).
// ============================================================================
__global__ __launch_bounds__(512, 6) void k_gemm2(
    const ushort_t* __restrict__ hbuf, const ushort_t* __restrict__ wt2,
    const float* __restrict__ b2,
    const int* __restrict__ assign, const int* __restrict__ cur,
    const int* __restrict__ segoff, const int* __restrict__ blk_e,
    const int* __restrict__ blk_m0, float* __restrict__ contrib) {
  const int nwg = 8 * TMX;                     // 576, divisible by 8
  int f = blockIdx.x;
  int lg = (f & 7) * (nwg >> 3) + (f >> 3);
  int m_idx = lg % TMX;
  int n_idx = lg / TMX;
  int e = blk_e[m_idx];
  if (e < 0) return;
  int m0 = blk_m0[m_idx];
  int count = cur[e];
  int n0 = n_idx << 7;
  int so = segoff[e];

  __shared__ __attribute__((aligned(16))) ushort_t A[3][128][32];
  __shared__ __attribute__((aligned(16))) ushort_t Bv[3][128][32];
  int tid = threadIdx.x;
  int lane = tid & 63, wid = tid >> 6;

  int srow = lane >> 2;
  int sunit = ((lane & 3) ^ ((lane >> 3) & 3)) << 3;
  int pA0 = m0 + wid * 16 + srow;
  int pa0 = (pA0 < count) ? pA0 : (count - 1);
  const ushort_t* gA0 = hbuf + (size_t)(so + pa0) * HID + sunit;
  const ushort_t* gB0 = wt2 + ((size_t)e * DIM + n0 + wid * 16 + srow) * HID + sunit;

  int wm = wid >> 2, wn = wid & 3;             // wave tile: 64(m) x 32(n)
  int lr = lane & 15, g = lane >> 4;
  int xsw = ((g ^ ((lr >> 1) & 3)) << 3);
  f32x4 acc[4][2];
  f32x4 zero = {0.f, 0.f, 0.f, 0.f};
#pragma unroll
  for (int m = 0; m < 4; m++)
#pragma unroll
    for (int n = 0; n < 2; n++) acc[m][n] = zero;

#define STAGE(SL, K0)                                          \
  { GLOAD_LDS16(gA0 + (K0), &A[SL][wid * 16][0]);              \
    GLOAD_LDS16(gB0 + (K0), &Bv[SL][wid * 16][0]); }

  STAGE(0, 0);
  STAGE(1, 32);
  VM2;
  __builtin_amdgcn_s_barrier();
  __builtin_amdgcn_sched_barrier(0);

  const int NT = HID / 32;                     // 128
  for (int t = 0; t < NT - 2; t += 3) {        // t = 0,3,...,123
    TILEK(0, t + 0, VM2, 1);
    TILEK(1, t + 1, VM2, 1);
    TILEK(2, t + 2, VM2, 1);
  }
  TILEK(0, NT - 2, VM0, 0);                    // tile 126, slot 0
  TILEK(1, NT - 1, VMN, 0);                    // tile 127, slot 1
#undef STAGE

#pragma unroll
  for (int m = 0; m < 4; m++) {
#pragma unroll
    for (int j = 0; j < 4; j++) {
      int p = m0 + wm * 64 + m * 16 + g * 4 + j;
      if (p >= count) continue;
      int a = assign[e * BT + p];
      int t = a >> 1, slot = a & 1;
      float* cr = contrib + ((size_t)slot * BT + t) * DIM;
#pragma unroll
      for (int n = 0; n < 2; n++) {
        int col = n0 + wn * 32 + n * 16 + lr;
        cr[col] = acc[m][n][j] + b2[e * DIM + col];
      }
    }
  }
}

// -------- combine: final = c0*probs[:,0] + c1*probs[:,1] --------
__global__ void k_combine(const float* __restrict__ contrib,
                          const float* __restrict__ probs01,
                          float* __restrict__ out) {
  int idx = blockIdx.x * blockDim.x + threadIdx.x;
  const int n4 = BT * DIM / 4;
  if (idx >= n4) return;
  int t = idx >> 8;
  float wA = probs01[t * 2 + 0], wB = probs01[t * 2 + 1];
  float4 c0 = ((const float4*)contrib)[idx];
  float4 c1 = ((const float4*)(contrib + (size_t)BT * DIM))[idx];
  float4 o;
  o.x = c0.x * wA + c1.x * wB;
  o.y = c0.y * wA + c1.y * wB;
  o.z = c0.z * wA + c1.z * wB;
  o.w = c0.w * wA + c1.w * wB;
  ((float4*)out)[idx] = o;
}

extern "C" void kernel_launch(void* const* d_in, const int* in_sizes, int n_in,
                              void* d_out, int out_size, void* d_ws, size_t ws_size,
                              hipStream_t stream) {
  const float* x  = (const float*)d_in[0];
  const float* wg = (const float*)d_in[1];
  const float* w1 = (const float*)d_in[2];
  const float* b1 = (const float*)d_in[3];
  const float* w2 = (const float*)d_in[4];
  const float* b2 = (const float*)d_in[5];
  float* out = (float*)d_out;
  float* logits_out = out + (size_t)BT * DIM;

  char* ws = (char*)d_ws;
  size_t off = 0;
  auto alloc = [&](size_t bytes) -> void* {
    void* p = ws + off;
    off = (off + bytes + 255) & ~(size_t)255;
    return p;
  };
  ushort_t* xbf    = (ushort_t*)alloc((size_t)BT * DIM * 2);
  ushort_t* wt1    = (ushort_t*)alloc((size_t)NE * HID * DIM * 2);
  ushort_t* wt2    = (ushort_t*)alloc((size_t)NE * DIM * HID * 2);
  ushort_t* hbuf   = (ushort_t*)alloc((size_t)2 * BT * HID * 2);
  float*    contrib= (float*)alloc((size_t)2 * BT * DIM * 4);
  float*    probs01= (float*)alloc((size_t)BT * 2 * 4);
  int*      assign = (int*)alloc((size_t)NE * BT * 4);
  int*      cur    = (int*)alloc(64);
  int*      segoff = (int*)alloc(64);
  int*      blk_e  = (int*)alloc(TMX * 4);
  int*      blk_m0 = (int*)alloc(TMX * 4);
  if (off > ws_size) return;

  hipMemsetAsync(cur, 0, NE * sizeof(int), stream);
  hipLaunchKernelGGL(k_prepass, dim3(8192 + BT), dim3(256), 0, stream,
                     x, wg, xbf, logits_out, probs01, assign, cur,
                     w1, wt1, w2, wt2);
  hipLaunchKernelGGL(k_plan, dim3(1), dim3(64), 0, stream, cur, segoff,
                     blk_e, blk_m0);
  hipLaunchKernelGGL(k_gemm1, dim3(32 * TMX), dim3(512), 0, stream,
                     xbf, wt1, b1, assign, cur, segoff, blk_e, blk_m0, hbuf);
  hipLaunchKernelGGL(k_gemm2, dim3(8 * TMX), dim3(512), 0, stream,
                     hbuf, wt2, b2, assign, cur, segoff, blk_e, blk_m0, contrib);
  hipLaunchKernelGGL(k_combine, dim3((BT * DIM / 4 + 255) / 256), dim3(256), 0, stream,
                     contrib, probs01, out);
}

// Round 16
// 431.703 us; speedup vs baseline: 1.0624x; 1.0624x over previous
//
#include <hip/hip_runtime.h>
#include <hip/hip_bf16.h>
#include <math.h>
#include <stdint.h>

#define BT  4096
#define DIM 1024
#define HID 4096
#define NE  8
#define TMX 72   // max active 128-row m-blocks

typedef __attribute__((ext_vector_type(8))) short short8v;
typedef __attribute__((ext_vector_type(4))) float f32x4;
typedef unsigned short ushort_t;

typedef __attribute__((address_space(1))) const void gas_void;
typedef __attribute__((address_space(3))) void las_void;
#define GLOAD_LDS16(g, l) __builtin_amdgcn_global_load_lds((gas_void*)(g), (las_void*)(l), 16, 0, 0)

__device__ inline ushort_t f2bf(float f) {
  __hip_bfloat16 b = __float2bfloat16(f);
  union { __hip_bfloat16 h; ushort_t u; } cv;
  cv.h = b;
  return cv.u;
}

// ============================================================================
// Transpose body (R16): 256 src-rows x 32 src-cols per block, 256 threads.
// Phase 1: 8x float4 reads/thread, 8 thr/row -> 128 B contiguous per row
//   (FULL DRAM sector; R15's 64 B granule caused 2x over-fetch, FETCH
//   139->270 MB).  Convert fp32->bf16 in registers, scatter ushort into
//   lt[32][264] (fire-and-forget writes, no latency chain).
// Phase 2: per dst col c: 32 lanes x short8v = 512 B contiguous dst write;
//   lt read = 8 dwords/bank (wave floor).  264-pad -> col bank-shift 4.
// ============================================================================
__device__ __forceinline__ void transpose256x32(
    const float* __restrict__ src, ushort_t* __restrict__ dst,
    int R, int C, int r0, int c0, int e, ushort_t (*lt)[264]) {
  const float* s = src + (size_t)e * R * C;
  ushort_t* d = dst + (size_t)e * R * C;
  int t = threadIdx.x;
#pragma unroll
  for (int i = 0; i < 8; i++) {
    int q = i * 256 + t;
    int r = q >> 3, c4 = (q & 7) * 4;
    float4 v = *(const float4*)&s[(size_t)(r0 + r) * C + c0 + c4];
    lt[c4 + 0][r] = f2bf(v.x);
    lt[c4 + 1][r] = f2bf(v.y);
    lt[c4 + 2][r] = f2bf(v.z);
    lt[c4 + 3][r] = f2bf(v.w);
  }
  __syncthreads();
  int wid = t >> 6, lane = t & 63;
#pragma unroll
  for (int ii = 0; ii < 4; ii++) {
    int c = wid * 2 + (lane >> 5) + 8 * ii;
    int r8 = (lane & 31) * 8;
    short8v ov = *(const short8v*)&lt[c][r8];
    *(short8v*)&d[(size_t)(c0 + c) * R + r0 + r8] = ov;
  }
}

// ============================================================================
// Merged pre-pass: w1t (4096 blocks) ∥ w2t (4096) ∥ prep+router (4096).
// cur[] zeroed by a 32B memset before this kernel.
// ============================================================================
__global__ __launch_bounds__(256) void k_prepass(
    const float* __restrict__ x, const float* __restrict__ wg,
    ushort_t* __restrict__ xbf, float* __restrict__ logits_out,
    float* __restrict__ probs01, int* __restrict__ assign,
    int* __restrict__ cur,
    const float* __restrict__ w1, ushort_t* __restrict__ wt1,
    const float* __restrict__ w2, ushort_t* __restrict__ wt2) {
  __shared__ __attribute__((aligned(16))) ushort_t lt[32][264];
  int id = blockIdx.x;
  if (id < 4096) {                             // w1t: R=1024,C=4096: 4rt x 128ct
    int e = id >> 9, rem = id & 511;
    int rt = rem >> 7, ct = rem & 127;
    transpose256x32(w1, wt1, DIM, HID, rt * 256, ct * 32, e, lt);
    return;
  }
  if (id < 8192) {                             // w2t: R=4096,C=1024: 16rt x 32ct
    int q = id - 4096;
    int e = q >> 9, rem = q & 511;
    int rt = rem >> 5, ct = rem & 31;
    transpose256x32(w2, wt2, HID, DIM, rt * 256, ct * 32, e, lt);
    return;
  }
  int t = id - 8192;                           // token 0..4095
  int tid = threadIdx.x;
  const float* xr = x + (size_t)t * DIM;
  float4 v = ((const float4*)xr)[tid];
  ushort4 o;
  o.x = f2bf(v.x); o.y = f2bf(v.y); o.z = f2bf(v.z); o.w = f2bf(v.w);
  ((ushort4*)(xbf + (size_t)t * DIM))[tid] = o;

  float vv[4] = {v.x, v.y, v.z, v.w};
  float part[NE];
#pragma unroll
  for (int e = 0; e < NE; e++) part[e] = 0.f;
#pragma unroll
  for (int i = 0; i < 4; i++) {
    const float4* wr = (const float4*)(wg + (size_t)(tid * 4 + i) * NE);
    float4 a = wr[0], b = wr[1];
    part[0] += vv[i] * a.x; part[1] += vv[i] * a.y;
    part[2] += vv[i] * a.z; part[3] += vv[i] * a.w;
    part[4] += vv[i] * b.x; part[5] += vv[i] * b.y;
    part[6] += vv[i] * b.z; part[7] += vv[i] * b.w;
  }
#pragma unroll
  for (int e = 0; e < NE; e++)
    for (int off = 32; off > 0; off >>= 1)
      part[e] += __shfl_xor(part[e], off);

  float (*red)[NE] = (float(*)[NE])lt;
  int lane = tid & 63, wv = tid >> 6;
  if (lane == 0) {
#pragma unroll
    for (int e = 0; e < NE; e++) red[wv][e] = part[e];
  }
  __syncthreads();
  if (tid == 0) {
    float s8[NE];
#pragma unroll
    for (int e = 0; e < NE; e++)
      s8[e] = red[0][e] + red[1][e] + red[2][e] + red[3][e];
    float m = s8[0];
    for (int e = 1; e < NE; e++) m = fmaxf(m, s8[e]);
    float p[NE], s = 0.f;
    for (int e = 0; e < NE; e++) { p[e] = expf(s8[e] - m); s += p[e]; }
    float inv = 1.f / s;
    for (int e = 0; e < NE; e++) p[e] *= inv;
    for (int e = 0; e < NE; e++) logits_out[(size_t)t * NE + e] = s8[e];
    probs01[t * 2 + 0] = p[0];
    probs01[t * 2 + 1] = p[1];
    int b0 = 0;
    for (int e = 1; e < NE; e++) if (p[e] > p[b0]) b0 = e;
    int b1 = (b0 == 0) ? 1 : 0;
    for (int e = 0; e < NE; e++) if (e != b0 && p[e] > p[b1]) b1 = e;
    int pos0 = atomicAdd(&cur[b0], 1);
    assign[b0 * BT + pos0] = t * 2 + 0;
    int pos1 = atomicAdd(&cur[b1], 1);
    assign[b1 * BT + pos1] = t * 2 + 1;
  }
}

// -------- plan: prefix offsets + flattened active 128-row block list --------
__global__ void k_plan(const int* __restrict__ cur, int* __restrict__ segoff,
                       int* __restrict__ blk_e, int* __restrict__ blk_m0) {
  if (threadIdx.x == 0 && blockIdx.x == 0) {
    int s = 0;
    for (int e = 0; e < NE; e++) { segoff[e] = s; s += cur[e]; }
    int t = 0;
    for (int e = 0; e < NE; e++) {
      int mb = (cur[e] + 127) >> 7;
      for (int i = 0; i < mb; i++) { blk_e[t] = e; blk_m0[t] = i << 7; t++; }
    }
    for (; t < TMX; t++) { blk_e[t] = -1; blk_m0[t] = 0; }
  }
}

// ============================================================================
// GEMM core (R12, verified 139us/55% occ): 128x128 tile, BK=32, RING-3 LDS
// = 48 KiB -> 3 blocks/CU, 512 thr = 8 waves (2M x 4N), wave tile 64x32,
// acc[4][2].  24 waves/CU = 6 waves/SIMD — the occupancy optimum:
// 2/4/6/8 waves/SIMD = 181/155/139/265(spill!) us.  launch_bounds(512,6)
// keeps VGPR=40 (no spill; (512,8) forced VGPR=32 -> 374MB scratch, R13).
// Per K-tile: reads(t, slot t%3) -> STAGE(t+2 -> slot (t+2)%3) -> vmcnt(2)
//   -> barrier -> sched_barrier -> setprio -> 8 MFMA -> setprio.
// ============================================================================
#define VM2 asm volatile("s_waitcnt vmcnt(2)" ::: "memory")
#define VM0 asm volatile("s_waitcnt vmcnt(0)" ::: "memory")
#define VMN do {} while (0)

#define TILEK(TB, T, VMX, DOSTG)                                                \
  { short8v bv[2], af[4];                                                       \
    _Pragma("unroll")                                                           \
    for (int n = 0; n < 2; n++)                                                 \
      bv[n] = *(const short8v*)&Bv[TB][wn * 32 + n * 16 + lr][xsw];             \
    _Pragma("unroll")                                                           \
    for (int m = 0; m < 4; m++)                                                 \
      af[m] = *(const short8v*)&A[TB][wm * 64 + m * 16 + lr][xsw];              \
    if (DOSTG) { STAGE((((TB) + 2) % 3), ((T) + 2) * 32); }                     \
    VMX;                                                                        \
    __builtin_amdgcn_s_barrier();                                               \
    __builtin_amdgcn_sched_barrier(0);                                          \
    __builtin_amdgcn_s_setprio(1);                                              \
    _Pragma("unroll")                                                           \
    for (int m = 0; m < 4; m++)                                                 \
      _Pragma("unroll")                                                         \
      for (int n = 0; n < 2; n++)                                               \
        acc[m][n] = __builtin_amdgcn_mfma_f32_16x16x32_bf16(af[m], bv[n],       \
                                                            acc[m][n], 0, 0, 0);\
    __builtin_amdgcn_s_setprio(0); }

// ============================================================================
// GEMM1: h = gelu(x_gathered @ w1^T + b1).  Grid 32n x TMX(72)m = 2304.
// ============================================================================
__global__ __launch_bounds__(512, 6) void k_gemm1(
    const ushort_t* __restrict__ xbf, const ushort_t* __restrict__ wt1,
    const float* __restrict__ b1,
    const int* __restrict__ assign, const int* __restrict__ cur,
    const int* __restrict__ segoff, const int* __restrict__ blk_e,
    const int* __restrict__ blk_m0, ushort_t* __restrict__ hbuf) {
  const int nwg = 32 * TMX;                    // 2304, divisible by 8
  int f = blockIdx.x;
  int lg = (f & 7) * (nwg >> 3) + (f >> 3);    // XCD chunk swizzle (bijective)
  int m_idx = lg % TMX;                        // m-inner: chunk reuses B-panels
  int n_idx = lg / TMX;
  int e = blk_e[m_idx];
  if (e < 0) return;
  int m0 = blk_m0[m_idx];
  int count = cur[e];
  int n0 = n_idx << 7;

  __shared__ __attribute__((aligned(16))) ushort_t A[3][128][32];
  __shared__ __attribute__((aligned(16))) ushort_t Bv[3][128][32];
  int tid = threadIdx.x;
  int lane = tid & 63, wid = tid >> 6;

  int srow = lane >> 2;                        // 0..15 within wave's 16 rows
  int sunit = ((lane & 3) ^ ((lane >> 3) & 3)) << 3;
  int pA0 = m0 + wid * 16 + srow;
  int tok0 = (pA0 < count) ? (assign[e * BT + pA0] >> 1) : 0;
  const ushort_t* gA0 = xbf + (size_t)tok0 * DIM + sunit;
  const ushort_t* gB0 = wt1 + ((size_t)e * HID + n0 + wid * 16 + srow) * DIM + sunit;

  int wm = wid >> 2, wn = wid & 3;             // wave tile: 64(m) x 32(n)
  int lr = lane & 15, g = lane >> 4;
  int xsw = ((g ^ ((lr >> 1) & 3)) << 3);
  f32x4 acc[4][2];
  f32x4 zero = {0.f, 0.f, 0.f, 0.f};
#pragma unroll
  for (int m = 0; m < 4; m++)
#pragma unroll
    for (int n = 0; n < 2; n++) acc[m][n] = zero;

#define STAGE(SL, K0)                                          \
  { GLOAD_LDS16(gA0 + (K0), &A[SL][wid * 16][0]);              \
    GLOAD_LDS16(gB0 + (K0), &Bv[SL][wid * 16][0]); }

  STAGE(0, 0);
  STAGE(1, 32);
  VM2;
  __builtin_amdgcn_s_barrier();
  __builtin_amdgcn_sched_barrier(0);

  const int NT = DIM / 32;                     // 32
  for (int t = 0; t < NT - 2; t += 3) {        // t = 0,3,...,27
    TILEK(0, t + 0, VM2, 1);
    TILEK(1, t + 1, VM2, 1);
    TILEK(2, t + 2, VM2, 1);
  }
  TILEK(0, NT - 2, VM0, 0);                    // tile 30, slot 0
  TILEK(1, NT - 1, VMN, 0);                    // tile 31, slot 1
#undef STAGE

  int so = segoff[e];
#pragma unroll
  for (int m = 0; m < 4; m++) {
#pragma unroll
    for (int j = 0; j < 4; j++) {
      int p = m0 + wm * 64 + m * 16 + g * 4 + j;
      if (p >= count) continue;
      ushort_t* hr = hbuf + (size_t)(so + p) * HID;
#pragma unroll
      for (int n = 0; n < 2; n++) {
        int col = n0 + wn * 32 + n * 16 + lr;
        float v = acc[m][n][j] + b1[e * HID + col];
        float gl = 0.5f * v * (1.0f + erff(v * 0.70710678118654752f));
        hr[col] = f2bf(gl);
      }
    }
  }
}

// ============================================================================
// GEMM2: contrib[slot][t] = h @ w2^T + b2.  Grid 8n x TMX(72)m = 576.
// 576 <= 768 -> the whole grid is co-resident (single dispatch round).
// ============================================================================
__global__ __launch_bounds__(512, 6) void k_gemm2(
    const ushort_t* __restrict__ hbuf, const ushort_t* __restrict__ wt2,
    const float* __restrict__ b2,
    const int* __restrict__ assign, const int* __restrict__ cur,
    const int* __restrict__ segoff, const int* __restrict__ blk_e,
    const int* __restrict__ blk_m0, float* __restrict__ contrib) {
  const int nwg = 8 * TMX;                     // 576, divisible by 8
  int f = blockIdx.x;
  int lg = (f & 7) * (nwg >> 3) + (f >> 3);
  int m_idx = lg % TMX;
  int n_idx = lg / TMX;
  int e = blk_e[m_idx];
  if (e < 0) return;
  int m0 = blk_m0[m_idx];
  int count = cur[e];
  int n0 = n_idx << 7;
  int so = segoff[e];

  __shared__ __attribute__((aligned(16))) ushort_t A[3][128][32];
  __shared__ __attribute__((aligned(16))) ushort_t Bv[3][128][32];
  int tid = threadIdx.x;
  int lane = tid & 63, wid = tid >> 6;

  int srow = lane >> 2;
  int sunit = ((lane & 3) ^ ((lane >> 3) & 3)) << 3;
  int pA0 = m0 + wid * 16 + srow;
  int pa0 = (pA0 < count) ? pA0 : (count - 1);
  const ushort_t* gA0 = hbuf + (size_t)(so + pa0) * HID + sunit;
  const ushort_t* gB0 = wt2 + ((size_t)e * DIM + n0 + wid * 16 + srow) * HID + sunit;

  int wm = wid >> 2, wn = wid & 3;             // wave tile: 64(m) x 32(n)
  int lr = lane & 15, g = lane >> 4;
  int xsw = ((g ^ ((lr >> 1) & 3)) << 3);
  f32x4 acc[4][2];
  f32x4 zero = {0.f, 0.f, 0.f, 0.f};
#pragma unroll
  for (int m = 0; m < 4; m++)
#pragma unroll
    for (int n = 0; n < 2; n++) acc[m][n] = zero;

#define STAGE(SL, K0)                                          \
  { GLOAD_LDS16(gA0 + (K0), &A[SL][wid * 16][0]);              \
    GLOAD_LDS16(gB0 + (K0), &Bv[SL][wid * 16][0]); }

  STAGE(0, 0);
  STAGE(1, 32);
  VM2;
  __builtin_amdgcn_s_barrier();
  __builtin_amdgcn_sched_barrier(0);

  const int NT = HID / 32;                     // 128
  for (int t = 0; t < NT - 2; t += 3) {        // t = 0,3,...,123
    TILEK(0, t + 0, VM2, 1);
    TILEK(1, t + 1, VM2, 1);
    TILEK(2, t + 2, VM2, 1);
  }
  TILEK(0, NT - 2, VM0, 0);                    // tile 126, slot 0
  TILEK(1, NT - 1, VMN, 0);                    // tile 127, slot 1
#undef STAGE

#pragma unroll
  for (int m = 0; m < 4; m++) {
#pragma unroll
    for (int j = 0; j < 4; j++) {
      int p = m0 + wm * 64 + m * 16 + g * 4 + j;
      if (p >= count) continue;
      int a = assign[e * BT + p];
      int t = a >> 1, slot = a & 1;
      float* cr = contrib + ((size_t)slot * BT + t) * DIM;
#pragma unroll
      for (int n = 0; n < 2; n++) {
        int col = n0 + wn * 32 + n * 16 + lr;
        cr[col] = acc[m][n][j] + b2[e * DIM + col];
      }
    }
  }
}

// -------- combine: final = c0*probs[:,0] + c1*probs[:,1] --------
__global__ void k_combine(const float* __restrict__ contrib,
                          const float* __restrict__ probs01,
                          float* __restrict__ out) {
  int idx = blockIdx.x * blockDim.x + threadIdx.x;
  const int n4 = BT * DIM / 4;
  if (idx >= n4) return;
  int t = idx >> 8;
  float wA = probs01[t * 2 + 0], wB = probs01[t * 2 + 1];
  float4 c0 = ((const float4*)contrib)[idx];
  float4 c1 = ((const float4*)(contrib + (size_t)BT * DIM))[idx];
  float4 o;
  o.x = c0.x * wA + c1.x * wB;
  o.y = c0.y * wA + c1.y * wB;
  o.z = c0.z * wA + c1.z * wB;
  o.w = c0.w * wA + c1.w * wB;
  ((float4*)out)[idx] = o;
}

extern "C" void kernel_launch(void* const* d_in, const int* in_sizes, int n_in,
                              void* d_out, int out_size, void* d_ws, size_t ws_size,
                              hipStream_t stream) {
  const float* x  = (const float*)d_in[0];
  const float* wg = (const float*)d_in[1];
  const float* w1 = (const float*)d_in[2];
  const float* b1 = (const float*)d_in[3];
  const float* w2 = (const float*)d_in[4];
  const float* b2 = (const float*)d_in[5];
  float* out = (float*)d_out;
  float* logits_out = out + (size_t)BT * DIM;

  char* ws = (char*)d_ws;
  size_t off = 0;
  auto alloc = [&](size_t bytes) -> void* {
    void* p = ws + off;
    off = (off + bytes + 255) & ~(size_t)255;
    return p;
  };
  ushort_t* xbf    = (ushort_t*)alloc((size_t)BT * DIM * 2);
  ushort_t* wt1    = (ushort_t*)alloc((size_t)NE * HID * DIM * 2);
  ushort_t* wt2    = (ushort_t*)alloc((size_t)NE * DIM * HID * 2);
  ushort_t* hbuf   = (ushort_t*)alloc((size_t)2 * BT * HID * 2);
  float*    contrib= (float*)alloc((size_t)2 * BT * DIM * 4);
  float*    probs01= (float*)alloc((size_t)BT * 2 * 4);
  int*      assign = (int*)alloc((size_t)NE * BT * 4);
  int*      cur    = (int*)alloc(64);
  int*      segoff = (int*)alloc(64);
  int*      blk_e  = (int*)alloc(TMX * 4);
  int*      blk_m0 = (int*)alloc(TMX * 4);
  if (off > ws_size) return;

  hipMemsetAsync(cur, 0, NE * sizeof(int), stream);
  hipLaunchKernelGGL(k_prepass, dim3(8192 + BT), dim3(256), 0, stream,
                     x, wg, xbf, logits_out, probs01, assign, cur,
                     w1, wt1, w2, wt2);
  hipLaunchKernelGGL(k_plan, dim3(1), dim3(64), 0, stream, cur, segoff,
                     blk_e, blk_m0);
  hipLaunchKernelGGL(k_gemm1, dim3(32 * TMX), dim3(512), 0, stream,
                     xbf, wt1, b1, assign, cur, segoff, blk_e, blk_m0, hbuf);
  hipLaunchKernelGGL(k_gemm2, dim3(8 * TMX), dim3(512), 0, stream,
                     hbuf, wt2, b2, assign, cur, segoff, blk_e, blk_m0, contrib);
  hipLaunchKernelGGL(k_combine, dim3((BT * DIM / 4 + 255) / 256), dim3(256), 0, stream,
                     contrib, probs01, out);
}

// Round 17
// 363.687 us; speedup vs baseline: 1.2610x; 1.1870x over previous
//
#include <hip/hip_runtime.h>
#include <hip/hip_bf16.h>
#include <math.h>
#include <stdint.h>

#define BT  4096
#define DIM 1024
#define HID 4096
#define NE  8
#define TMX 72   // max active 128-row m-blocks

typedef __attribute__((ext_vector_type(8))) short short8v;
typedef __attribute__((ext_vector_type(4))) float f32x4;
typedef unsigned short ushort_t;

typedef __attribute__((address_space(1))) const void gas_void;
typedef __attribute__((address_space(3))) void las_void;
#define GLOAD_LDS16(g, l) __builtin_amdgcn_global_load_lds((gas_void*)(g), (las_void*)(l), 16, 0, 0)

__device__ inline ushort_t f2bf(float f) {
  __hip_bfloat16 b = __float2bfloat16(f);
  union { __hip_bfloat16 h; ushort_t u; } cv;
  cv.h = b;
  return cv.u;
}

// ============================================================================
// Transpose body (R16, kept): 256 src-rows x 32 src-cols, 256 threads.
// Phase 1: 8x float4/thread, 8 thr/row = 128 B full-sector reads; convert in
// registers; scatter ushort to lt[32][264] (fire-and-forget).
// Phase 2: per dst col, 512 B contiguous writes; lt read 8 dwords/bank.
// ============================================================================
__device__ __forceinline__ void transpose256x32(
    const float* __restrict__ src, ushort_t* __restrict__ dst,
    int R, int C, int r0, int c0, int e, ushort_t (*lt)[264]) {
  const float* s = src + (size_t)e * R * C;
  ushort_t* d = dst + (size_t)e * R * C;
  int t = threadIdx.x;
#pragma unroll
  for (int i = 0; i < 8; i++) {
    int q = i * 256 + t;
    int r = q >> 3, c4 = (q & 7) * 4;
    float4 v = *(const float4*)&s[(size_t)(r0 + r) * C + c0 + c4];
    lt[c4 + 0][r] = f2bf(v.x);
    lt[c4 + 1][r] = f2bf(v.y);
    lt[c4 + 2][r] = f2bf(v.z);
    lt[c4 + 3][r] = f2bf(v.w);
  }
  __syncthreads();
  int wid = t >> 6, lane = t & 63;
#pragma unroll
  for (int ii = 0; ii < 4; ii++) {
    int c = wid * 2 + (lane >> 5) + 8 * ii;
    int r8 = (lane & 31) * 8;
    short8v ov = *(const short8v*)&lt[c][r8];
    *(short8v*)&d[(size_t)(c0 + c) * R + r0 + r8] = ov;
  }
}

// ============================================================================
// Merged pre-pass: w1t (4096 blocks) ∥ w2t (4096) ∥ prep+router (4096).
// R17: NO GLOBAL ATOMICS — router writes packed top01[t] = b0 | b1<<8.
// (Three transpose variants all pinned at ~190us; the invariant was 8192
// same-cache-line device atomicAdds serializing through one L2 bank.)
// ============================================================================
__global__ __launch_bounds__(256) void k_prepass(
    const float* __restrict__ x, const float* __restrict__ wg,
    ushort_t* __restrict__ xbf, float* __restrict__ logits_out,
    float* __restrict__ probs01, int* __restrict__ top01,
    const float* __restrict__ w1, ushort_t* __restrict__ wt1,
    const float* __restrict__ w2, ushort_t* __restrict__ wt2) {
  __shared__ __attribute__((aligned(16))) ushort_t lt[32][264];
  int id = blockIdx.x;
  if (id < 4096) {                             // w1t: R=1024,C=4096: 4rt x 128ct
    int e = id >> 9, rem = id & 511;
    int rt = rem >> 7, ct = rem & 127;
    transpose256x32(w1, wt1, DIM, HID, rt * 256, ct * 32, e, lt);
    return;
  }
  if (id < 8192) {                             // w2t: R=4096,C=1024: 16rt x 32ct
    int q = id - 4096;
    int e = q >> 9, rem = q & 511;
    int rt = rem >> 5, ct = rem & 31;
    transpose256x32(w2, wt2, HID, DIM, rt * 256, ct * 32, e, lt);
    return;
  }
  int t = id - 8192;                           // token 0..4095
  int tid = threadIdx.x;
  const float* xr = x + (size_t)t * DIM;
  float4 v = ((const float4*)xr)[tid];
  ushort4 o;
  o.x = f2bf(v.x); o.y = f2bf(v.y); o.z = f2bf(v.z); o.w = f2bf(v.w);
  ((ushort4*)(xbf + (size_t)t * DIM))[tid] = o;

  float vv[4] = {v.x, v.y, v.z, v.w};
  float part[NE];
#pragma unroll
  for (int e = 0; e < NE; e++) part[e] = 0.f;
#pragma unroll
  for (int i = 0; i < 4; i++) {
    const float4* wr = (const float4*)(wg + (size_t)(tid * 4 + i) * NE);
    float4 a = wr[0], b = wr[1];
    part[0] += vv[i] * a.x; part[1] += vv[i] * a.y;
    part[2] += vv[i] * a.z; part[3] += vv[i] * a.w;
    part[4] += vv[i] * b.x; part[5] += vv[i] * b.y;
    part[6] += vv[i] * b.z; part[7] += vv[i] * b.w;
  }
#pragma unroll
  for (int e = 0; e < NE; e++)
    for (int off = 32; off > 0; off >>= 1)
      part[e] += __shfl_xor(part[e], off);

  float (*red)[NE] = (float(*)[NE])lt;
  int lane = tid & 63, wv = tid >> 6;
  if (lane == 0) {
#pragma unroll
    for (int e = 0; e < NE; e++) red[wv][e] = part[e];
  }
  __syncthreads();
  if (tid == 0) {
    float s8[NE];
#pragma unroll
    for (int e = 0; e < NE; e++)
      s8[e] = red[0][e] + red[1][e] + red[2][e] + red[3][e];
    float m = s8[0];
    for (int e = 1; e < NE; e++) m = fmaxf(m, s8[e]);
    float p[NE], s = 0.f;
    for (int e = 0; e < NE; e++) { p[e] = expf(s8[e] - m); s += p[e]; }
    float inv = 1.f / s;
    for (int e = 0; e < NE; e++) p[e] *= inv;
    for (int e = 0; e < NE; e++) logits_out[(size_t)t * NE + e] = s8[e];
    probs01[t * 2 + 0] = p[0];
    probs01[t * 2 + 1] = p[1];
    int b0 = 0;
    for (int e = 1; e < NE; e++) if (p[e] > p[b0]) b0 = e;
    int b1 = (b0 == 0) ? 1 : 0;
    for (int e = 0; e < NE; e++) if (e != b0 && p[e] > p[b1]) b1 = e;
    top01[t] = b0 | (b1 << 8);                 // no global atomics
  }
}

// ============================================================================
// k_bin (R17): single block, 1024 thr.  LDS-atomic binning (8192 ops over 8
// LDS words ~ few us, no L2 serialization) + segoff/blk-list planning.
// Within-expert order is arbitrary (as with the old global atomics) — each
// token's output is independent of its row position.
// ============================================================================
__global__ __launch_bounds__(1024) void k_bin(
    const int* __restrict__ top01, int* __restrict__ assign,
    int* __restrict__ cur, int* __restrict__ segoff,
    int* __restrict__ blk_e, int* __restrict__ blk_m0) {
  __shared__ int sc[NE];
  int tid = threadIdx.x;
  if (tid < NE) sc[tid] = 0;
  __syncthreads();
#pragma unroll
  for (int i = 0; i < 4; i++) {
    int t = tid + i * 1024;
    int vv = top01[t];
    int b0 = vv & 255, b1 = (vv >> 8) & 255;
    int p0 = atomicAdd(&sc[b0], 1);
    assign[b0 * BT + p0] = t * 2 + 0;
    int p1 = atomicAdd(&sc[b1], 1);
    assign[b1 * BT + p1] = t * 2 + 1;
  }
  __syncthreads();
  if (tid == 0) {
    int s = 0;
    for (int e = 0; e < NE; e++) { cur[e] = sc[e]; segoff[e] = s; s += sc[e]; }
    int t = 0;
    for (int e = 0; e < NE; e++) {
      int mb = (sc[e] + 127) >> 7;
      for (int i = 0; i < mb; i++) { blk_e[t] = e; blk_m0[t] = i << 7; t++; }
    }
    for (; t < TMX; t++) { blk_e[t] = -1; blk_m0[t] = 0; }
  }
}

// ============================================================================
// GEMM core (R12, verified 139us/55% occ): 128x128 tile, BK=32, RING-3 LDS
// = 48 KiB -> 3 blocks/CU, 512 thr = 8 waves (2M x 4N), wave tile 64x32,
// acc[4][2].  24 waves/CU = 6 waves/SIMD — the occupancy optimum:
// 2/4/6/8 waves/SIMD = 181/155/139/265(spill!) us.  launch_bounds(512,6)
// keeps VGPR=40 (no spill).
// Per K-tile: reads(t, slot t%3) -> STAGE(t+2 -> slot (t+2)%3) -> vmcnt(2)
//   -> barrier -> sched_barrier -> setprio -> 8 MFMA -> setprio.
// ============================================================================
#define VM2 asm volatile("s_waitcnt vmcnt(2)" ::: "memory")
#define VM0 asm volatile("s_waitcnt vmcnt(0)" ::: "memory")
#define VMN do {} while (0)

#define TILEK(TB, T, VMX, DOSTG)                                                \
  { short8v bv[2], af[4];                                                       \
    _Pragma("unroll")                                                           \
    for (int n = 0; n < 2; n++)                                                 \
      bv[n] = *(const short8v*)&Bv[TB][wn * 32 + n * 16 + lr][xsw];             \
    _Pragma("unroll")                                                           \
    for (int m = 0; m < 4; m++)                                                 \
      af[m] = *(const short8v*)&A[TB][wm * 64 + m * 16 + lr][xsw];              \
    if (DOSTG) { STAGE((((TB) + 2) % 3), ((T) + 2) * 32); }                     \
    VMX;                                                                        \
    __builtin_amdgcn_s_barrier();                                               \
    __builtin_amdgcn_sched_barrier(0);                                          \
    __builtin_amdgcn_s_setprio(1);                                              \
    _Pragma("unroll")                                                           \
    for (int m = 0; m < 4; m++)                                                 \
      _Pragma("unroll")                                                         \
      for (int n = 0; n < 2; n++)                                               \
        acc[m][n] = __builtin_amdgcn_mfma_f32_16x16x32_bf16(af[m], bv[n],       \
                                                            acc[m][n], 0, 0, 0);\
    __builtin_amdgcn_s_setprio(0); }

// ============================================================================
// GEMM1: h = gelu(x_gathered @ w1^T + b1).  Grid 32n x TMX(72)m = 2304.
// ============================================================================
__global__ __launch_bounds__(512, 6) void k_gemm1(
    const ushort_t* __restrict__ xbf, const ushort_t* __restrict__ wt1,
    const float* __restrict__ b1,
    const int* __restrict__ assign, const int* __restrict__ cur,
    const int* __restrict__ segoff, const int* __restrict__ blk_e,
    const int* __restrict__ blk_m0, ushort_t* __restrict__ hbuf) {
  const int nwg = 32 * TMX;                    // 2304, divisible by 8
  int f = blockIdx.x;
  int lg = (f & 7) * (nwg >> 3) + (f >> 3);    // XCD chunk swizzle (bijective)
  int m_idx = lg % TMX;                        // m-inner: chunk reuses B-panels
  int n_idx = lg / TMX;
  int e = blk_e[m_idx];
  if (e < 0) return;
  int m0 = blk_m0[m_idx];
  int count = cur[e];
  int n0 = n_idx << 7;

  __shared__ __attribute__((aligned(16))) ushort_t A[3][128][32];
  __shared__ __attribute__((aligned(16))) ushort_t Bv[3][128][32];
  int tid = threadIdx.x;
  int lane = tid & 63, wid = tid >> 6;

  int srow = lane >> 2;                        // 0..15 within wave's 16 rows
  int sunit = ((lane & 3) ^ ((lane >> 3) & 3)) << 3;
  int pA0 = m0 + wid * 16 + srow;
  int tok0 = (pA0 < count) ? (assign[e * BT + pA0] >> 1) : 0;
  const ushort_t* gA0 = xbf + (size_t)tok0 * DIM + sunit;
  const ushort_t* gB0 = wt1 + ((size_t)e * HID + n0 + wid * 16 + srow) * DIM + sunit;

  int wm = wid >> 2, wn = wid & 3;             // wave tile: 64(m) x 32(n)
  int lr = lane & 15, g = lane >> 4;
  int xsw = ((g ^ ((lr >> 1) & 3)) << 3);
  f32x4 acc[4][2];
  f32x4 zero = {0.f, 0.f, 0.f, 0.f};
#pragma unroll
  for (int m = 0; m < 4; m++)
#pragma unroll
    for (int n = 0; n < 2; n++) acc[m][n] = zero;

#define STAGE(SL, K0)                                          \
  { GLOAD_LDS16(gA0 + (K0), &A[SL][wid * 16][0]);              \
    GLOAD_LDS16(gB0 + (K0), &Bv[SL][wid * 16][0]); }

  STAGE(0, 0);
  STAGE(1, 32);
  VM2;
  __builtin_amdgcn_s_barrier();
  __builtin_amdgcn_sched_barrier(0);

  const int NT = DIM / 32;                     // 32
  for (int t = 0; t < NT - 2; t += 3) {        // t = 0,3,...,27
    TILEK(0, t + 0, VM2, 1);
    TILEK(1, t + 1, VM2, 1);
    TILEK(2, t + 2, VM2, 1);
  }
  TILEK(0, NT - 2, VM0, 0);                    // tile 30, slot 0
  TILEK(1, NT - 1, VMN, 0);                    // tile 31, slot 1
#undef STAGE

  int so = segoff[e];
#pragma unroll
  for (int m = 0; m < 4; m++) {
#pragma unroll
    for (int j = 0; j < 4; j++) {
      int p = m0 + wm * 64 + m * 16 + g * 4 + j;
      if (p >= count) continue;
      ushort_t* hr = hbuf + (size_t)(so + p) * HID;
#pragma unroll
      for (int n = 0; n < 2; n++) {
        int col = n0 + wn * 32 + n * 16 + lr;
        float v = acc[m][n][j] + b1[e * HID + col];
        float gl = 0.5f * v * (1.0f + erff(v * 0.70710678118654752f));
        hr[col] = f2bf(gl);
      }
    }
  }
}

// ============================================================================
// GEMM2: contrib[slot][t] = h @ w2^T + b2.  Grid 8n x TMX(72)m = 576.
// 576 <= 768 -> the whole grid is co-resident (single dispatch round).
// ============================================================================
__global__ __launch_bounds__(512, 6) void k_gemm2(
    const ushort_t* __restrict__ hbuf, const ushort_t* __restrict__ wt2,
    const float* __restrict__ b2,
    const int* __restrict__ assign, const int* __restrict__ cur,
    const int* __restrict__ segoff, const int* __restrict__ blk_e,
    const int* __restrict__ blk_m0, float* __restrict__ contrib) {
  const int nwg = 8 * TMX;                     // 576, divisible by 8
  int f = blockIdx.x;
  int lg = (f & 7) * (nwg >> 3) + (f >> 3);
  int m_idx = lg % TMX;
  int n_idx = lg / TMX;
  int e = blk_e[m_idx];
  if (e < 0) return;
  int m0 = blk_m0[m_idx];
  int count = cur[e];
  int n0 = n_idx << 7;
  int so = segoff[e];

  __shared__ __attribute__((aligned(16))) ushort_t A[3][128][32];
  __shared__ __attribute__((aligned(16))) ushort_t Bv[3][128][32];
  int tid = threadIdx.x;
  int lane = tid & 63, wid = tid >> 6;

  int srow = lane >> 2;
  int sunit = ((lane & 3) ^ ((lane >> 3) & 3)) << 3;
  int pA0 = m0 + wid * 16 + srow;
  int pa0 = (pA0 < count) ? pA0 : (count - 1);
  const ushort_t* gA0 = hbuf + (size_t)(so + pa0) * HID + sunit;
  const ushort_t* gB0 = wt2 + ((size_t)e * DIM + n0 + wid * 16 + srow) * HID + sunit;

  int wm = wid >> 2, wn = wid & 3;             // wave tile: 64(m) x 32(n)
  int lr = lane & 15, g = lane >> 4;
  int xsw = ((g ^ ((lr >> 1) & 3)) << 3);
  f32x4 acc[4][2];
  f32x4 zero = {0.f, 0.f, 0.f, 0.f};
#pragma unroll
  for (int m = 0; m < 4; m++)
#pragma unroll
    for (int n = 0; n < 2; n++) acc[m][n] = zero;

#define STAGE(SL, K0)                                          \
  { GLOAD_LDS16(gA0 + (K0), &A[SL][wid * 16][0]);              \
    GLOAD_LDS16(gB0 + (K0), &Bv[SL][wid * 16][0]); }

  STAGE(0, 0);
  STAGE(1, 32);
  VM2;
  __builtin_amdgcn_s_barrier();
  __builtin_amdgcn_sched_barrier(0);

  const int NT = HID / 32;                     // 128
  for (int t = 0; t < NT - 2; t += 3) {        // t = 0,3,...,123
    TILEK(0, t + 0, VM2, 1);
    TILEK(1, t + 1, VM2, 1);
    TILEK(2, t + 2, VM2, 1);
  }
  TILEK(0, NT - 2, VM0, 0);                    // tile 126, slot 0
  TILEK(1, NT - 1, VMN, 0);                    // tile 127, slot 1
#undef STAGE

#pragma unroll
  for (int m = 0; m < 4; m++) {
#pragma unroll
    for (int j = 0; j < 4; j++) {
      int p = m0 + wm * 64 + m * 16 + g * 4 + j;
      if (p >= count) continue;
      int a = assign[e * BT + p];
      int t = a >> 1, slot = a & 1;
      float* cr = contrib + ((size_t)slot * BT + t) * DIM;
#pragma unroll
      for (int n = 0; n < 2; n++) {
        int col = n0 + wn * 32 + n * 16 + lr;
        cr[col] = acc[m][n][j] + b2[e * DIM + col];
      }
    }
  }
}

// -------- combine: final = c0*probs[:,0] + c1*probs[:,1] --------
__global__ void k_combine(const float* __restrict__ contrib,
                          const float* __restrict__ probs01,
                          float* __restrict__ out) {
  int idx = blockIdx.x * blockDim.x + threadIdx.x;
  const int n4 = BT * DIM / 4;
  if (idx >= n4) return;
  int t = idx >> 8;
  float wA = probs01[t * 2 + 0], wB = probs01[t * 2 + 1];
  float4 c0 = ((const float4*)contrib)[idx];
  float4 c1 = ((const float4*)(contrib + (size_t)BT * DIM))[idx];
  float4 o;
  o.x = c0.x * wA + c1.x * wB;
  o.y = c0.y * wA + c1.y * wB;
  o.z = c0.z * wA + c1.z * wB;
  o.w = c0.w * wA + c1.w * wB;
  ((float4*)out)[idx] = o;
}

extern "C" void kernel_launch(void* const* d_in, const int* in_sizes, int n_in,
                              void* d_out, int out_size, void* d_ws, size_t ws_size,
                              hipStream_t stream) {
  const float* x  = (const float*)d_in[0];
  const float* wg = (const float*)d_in[1];
  const float* w1 = (const float*)d_in[2];
  const float* b1 = (const float*)d_in[3];
  const float* w2 = (const float*)d_in[4];
  const float* b2 = (const float*)d_in[5];
  float* out = (float*)d_out;
  float* logits_out = out + (size_t)BT * DIM;

  char* ws = (char*)d_ws;
  size_t off = 0;
  auto alloc = [&](size_t bytes) -> void* {
    void* p = ws + off;
    off = (off + bytes + 255) & ~(size_t)255;
    return p;
  };
  ushort_t* xbf    = (ushort_t*)alloc((size_t)BT * DIM * 2);
  ushort_t* wt1    = (ushort_t*)alloc((size_t)NE * HID * DIM * 2);
  ushort_t* wt2    = (ushort_t*)alloc((size_t)NE * DIM * HID * 2);
  ushort_t* hbuf   = (ushort_t*)alloc((size_t)2 * BT * HID * 2);
  float*    contrib= (float*)alloc((size_t)2 * BT * DIM * 4);
  float*    probs01= (float*)alloc((size_t)BT * 2 * 4);
  int*      assign = (int*)alloc((size_t)NE * BT * 4);
  int*      top01  = (int*)alloc((size_t)BT * 4);
  int*      cur    = (int*)alloc(64);
  int*      segoff = (int*)alloc(64);
  int*      blk_e  = (int*)alloc(TMX * 4);
  int*      blk_m0 = (int*)alloc(TMX * 4);
  if (off > ws_size) return;

  hipLaunchKernelGGL(k_prepass, dim3(8192 + BT), dim3(256), 0, stream,
                     x, wg, xbf, logits_out, probs01, top01,
                     w1, wt1, w2, wt2);
  hipLaunchKernelGGL(k_bin, dim3(1), dim3(1024), 0, stream,
                     top01, assign, cur, segoff, blk_e, blk_m0);
  hipLaunchKernelGGL(k_gemm1, dim3(32 * TMX), dim3(512), 0, stream,
                     xbf, wt1, b1, assign, cur, segoff, blk_e, blk_m0, hbuf);
  hipLaunchKernelGGL(k_gemm2, dim3(8 * TMX), dim3(512), 0, stream,
                     hbuf, wt2, b2, assign, cur, segoff, blk_e, blk_m0, contrib);
  hipLaunchKernelGGL(k_combine, dim3((BT * DIM / 4 + 255) / 256), dim3(256), 0, stream,
                     contrib, probs01, out);
}